// Round 1
// baseline (288.672 us; speedup 1.0000x reference)
//
#include <hip/hip_runtime.h>
#include <hip/hip_bf16.h>

// Problem constants
#define N_U 1024          // IN_U (rows of weight, K-dim of final GEMM)
#define M_U 1024          // OUT_U (cols of weight, N-dim of final GEMM)
#define BATCH 4096

// ws layout (float offsets):
//   rs:  [0, 1024)           rowsum(weight)
//   cs:  [1024, 2048)        colsum(weight)
//   rn:  [2048, 12288)       per-n layer1 table [1024][10]
//   cm:  [12288, 22528)      per-m layer1 table [1024][10]
//   Wn:  [24576, 24576+1M)   new_weight f32 [1024][1024]

// ---------------------------------------------------------------------------
// Kernel 1: row sums and column sums of weight. Block b handles row b
// (coalesced) and column b (strided; L2 absorbs the 16x line waste on 4 MB).
__global__ void k_sums(const float* __restrict__ w,
                       float* __restrict__ rs, float* __restrict__ cs) {
    int b = blockIdx.x, t = threadIdx.x;
    float pr = 0.f, pc = 0.f;
    for (int j = t; j < 1024; j += 256) {
        pr += w[b * 1024 + j];
        pc += w[j * 1024 + b];
    }
    __shared__ float r1[256], r2[256];
    r1[t] = pr; r2[t] = pc;
    __syncthreads();
    for (int s = 128; s > 0; s >>= 1) {
        if (t < s) { r1[t] += r1[t + s]; r2[t] += r2[t + s]; }
        __syncthreads();
    }
    if (t == 0) { rs[b] = r1[0]; cs[b] = r2[0]; }
}

// ---------------------------------------------------------------------------
// Kernel 2: per-row (rn) and per-col (cm) layer-1 tables.
// pre1[n,m,h] = w*a[h] + rn[n,h] + cm[m,h]; this builds rn/cm from the
// analytic collapse of hidden / fwd_hs / bwd_hs (bit features of n and m).
__global__ void k_tables(const float* __restrict__ rs, const float* __restrict__ cs,
                         const float* __restrict__ W1, const float* __restrict__ b1,
                         float* __restrict__ rn, float* __restrict__ cm) {
    int id = blockIdx.x * 256 + threadIdx.x;
    if (id >= 2048) return;
    int n = id & 1023;
    int side = id >> 10;
    const float inv = 1.0f / 1023.0f;
    if (side == 0) {
        float r = rs[n];
        for (int h = 0; h < 10; h++) {
            float v = r * W1[2 * 10 + h] * inv;
            for (int j = 0; j < 10; j++) {
                float bit = (float)((n >> (9 - j)) & 1);
                // hidden(j<10)=bit(n): idx 3+j; bwd_hs(j<10)=bit(n): idx 43+j;
                // fwd_hs(j<10)=(512-bit(n))/1023: idx 23+j
                v += bit * (W1[(3 + j) * 10 + h] + W1[(43 + j) * 10 + h]
                            - W1[(23 + j) * 10 + h] * inv);
                v += (512.0f * inv) * W1[(23 + j) * 10 + h];
            }
            rn[n * 10 + h] = v;
        }
    } else {
        float c = cs[n];  // n is really m here
        for (int h = 0; h < 10; h++) {
            float v = c * W1[1 * 10 + h] * inv + b1[h];
            for (int j = 0; j < 10; j++) {
                float bit = (float)((n >> (9 - j)) & 1);
                // hidden(j>=10)=bit(m): idx 13+j; fwd_hs(j>=10)=bit(m): idx 33+j;
                // bwd_hs(j>=10)=(512-bit(m))/1023: idx 53+j
                v += bit * (W1[(13 + j) * 10 + h] + W1[(33 + j) * 10 + h]
                            - W1[(53 + j) * 10 + h] * inv);
                v += (512.0f * inv) * W1[(53 + j) * 10 + h];
            }
            cm[n * 10 + h] = v;
        }
    }
}

// ---------------------------------------------------------------------------
// Kernel 3: new_weight = weight + MLP(feat)[...,0].
// One thread per cell; layer1 via rank-1+tables, layer2 10x10, layer3 dot W3[:,0].
__global__ void k_newweight(const float* __restrict__ w,
                            const float* __restrict__ rn, const float* __restrict__ cm,
                            const float* __restrict__ W1, const float* __restrict__ W2,
                            const float* __restrict__ b2, const float* __restrict__ W3,
                            const float* __restrict__ b3, float* __restrict__ Wn) {
    __shared__ float sW2[100], sb2[10], sw3[10], sa[10], srn[10];
    int t = threadIdx.x;
    int g = blockIdx.x * 256 + t;
    int n = g >> 10, m = g & 1023;  // block spans one n (256 | 1024)
    if (t < 100) sW2[t] = W2[t];
    if (t >= 128 && t < 138) sb2[t - 128] = b2[t - 128];
    if (t >= 160 && t < 170) sw3[t - 160] = W3[(t - 160) * 21];  // W3[:,0], row stride 21
    if (t >= 192 && t < 202) {
        int h = t - 192;
        sa[h] = W1[h] - (W1[10 + h] + W1[20 + h]) * (1.0f / 1023.0f);
    }
    if (t >= 224 && t < 234) { int h = t - 224; srn[h] = rn[n * 10 + h]; }
    __syncthreads();
    float wv = w[g];
    float h1[10];
    #pragma unroll
    for (int h = 0; h < 10; h++)
        h1[h] = fmaxf(wv * sa[h] + srn[h] + cm[m * 10 + h], 0.0f);
    float u = b3[0];
    #pragma unroll
    for (int k = 0; k < 10; k++) {
        float h2 = sb2[k];
        #pragma unroll
        for (int h = 0; h < 10; h++) h2 += h1[h] * sW2[h * 10 + k];
        u += fmaxf(h2, 0.0f) * sw3[k];
    }
    Wn[g] = wv + u;
}

// ---------------------------------------------------------------------------
// Kernel 4: C = relu(A @ B), A=[4096,1024] f32, B=Wn [1024,1024] f32.
// BM=128, BN=64, BK=16; 256 threads; 8x4 micro-tile per thread.
// A staged transposed in LDS ([k][m], pad 132 -> worst 2-way aliasing = free).
__global__ __launch_bounds__(256) void k_gemm(const float* __restrict__ A,
                                              const float* __restrict__ B,
                                              float* __restrict__ C) {
    __shared__ float sA[16 * 132];  // [k][m] padded
    __shared__ float sB[16 * 64];   // [k][n]
    int tid = threadIdx.x;
    int tx = tid & 15, ty = tid >> 4;
    int n0 = blockIdx.x * 64, m0 = blockIdx.y * 128;
    float acc[8][4];
    #pragma unroll
    for (int i = 0; i < 8; i++)
        #pragma unroll
        for (int j = 0; j < 4; j++) acc[i][j] = 0.f;

    for (int k0 = 0; k0 < 1024; k0 += 16) {
        __syncthreads();
        // A-tile: 128 rows x 16 k, 2 float4 per thread, stored transposed
        #pragma unroll
        for (int s = 0; s < 2; s++) {
            int f = tid + 256 * s;
            int row = f >> 2, cseg = f & 3;
            const float4 v = *(const float4*)&A[(m0 + row) * 1024 + k0 + cseg * 4];
            sA[(cseg * 4 + 0) * 132 + row] = v.x;
            sA[(cseg * 4 + 1) * 132 + row] = v.y;
            sA[(cseg * 4 + 2) * 132 + row] = v.z;
            sA[(cseg * 4 + 3) * 132 + row] = v.w;
        }
        // B-tile: 16 rows x 64 n, 1 float4 per thread
        {
            int row = tid >> 4, cseg = tid & 15;
            *(float4*)&sB[row * 64 + cseg * 4] =
                *(const float4*)&B[(k0 + row) * 1024 + n0 + cseg * 4];
        }
        __syncthreads();
        #pragma unroll
        for (int kk = 0; kk < 16; kk++) {
            float4 a0 = *(const float4*)&sA[kk * 132 + ty * 8];
            float4 a1 = *(const float4*)&sA[kk * 132 + ty * 8 + 4];
            float4 bv = *(const float4*)&sB[kk * 64 + tx * 4];
            float av[8] = {a0.x, a0.y, a0.z, a0.w, a1.x, a1.y, a1.z, a1.w};
            float bb[4] = {bv.x, bv.y, bv.z, bv.w};
            #pragma unroll
            for (int i = 0; i < 8; i++)
                #pragma unroll
                for (int j = 0; j < 4; j++) acc[i][j] += av[i] * bb[j];
        }
    }
    #pragma unroll
    for (int i = 0; i < 8; i++) {
        float4 r;
        r.x = fmaxf(acc[i][0], 0.f);
        r.y = fmaxf(acc[i][1], 0.f);
        r.z = fmaxf(acc[i][2], 0.f);
        r.w = fmaxf(acc[i][3], 0.f);
        *(float4*)&C[(m0 + ty * 8 + i) * 1024 + n0 + tx * 4] = r;
    }
}

// ---------------------------------------------------------------------------
// Kernel 5: in-place row softmax over 1024 cols (input already relu'd >= 0).
__global__ void k_softmax(float* __restrict__ C) {
    int row = blockIdx.x, t = threadIdx.x;
    float4 v = *(float4*)&C[row * 1024 + t * 4];
    __shared__ float red[256];
    float lm = fmaxf(fmaxf(v.x, v.y), fmaxf(v.z, v.w));
    red[t] = lm;
    __syncthreads();
    for (int s = 128; s > 0; s >>= 1) {
        if (t < s) red[t] = fmaxf(red[t], red[t + s]);
        __syncthreads();
    }
    float mx = red[0];
    __syncthreads();
    float4 e;
    e.x = __expf(v.x - mx); e.y = __expf(v.y - mx);
    e.z = __expf(v.z - mx); e.w = __expf(v.w - mx);
    float ls = e.x + e.y + e.z + e.w;
    red[t] = ls;
    __syncthreads();
    for (int s = 128; s > 0; s >>= 1) {
        if (t < s) red[t] += red[t + s];
        __syncthreads();
    }
    float inv = 1.0f / red[0];
    e.x *= inv; e.y *= inv; e.z *= inv; e.w *= inv;
    *(float4*)&C[row * 1024 + t * 4] = e;
}

// ---------------------------------------------------------------------------
extern "C" void kernel_launch(void* const* d_in, const int* in_sizes, int n_in,
                              void* d_out, int out_size, void* d_ws, size_t ws_size,
                              hipStream_t stream) {
    const float* X  = (const float*)d_in[0];   // [4096,1024]
    const float* W  = (const float*)d_in[1];   // [1024,1024]
    // d_in[2] = hidden: computed analytically, never read
    const float* W1 = (const float*)d_in[3];   // [63,10]
    const float* b1 = (const float*)d_in[4];   // [10]
    const float* W2 = (const float*)d_in[5];   // [10,10]
    const float* b2 = (const float*)d_in[6];   // [10]
    const float* W3 = (const float*)d_in[7];   // [10,21]
    const float* b3 = (const float*)d_in[8];   // [21]

    float* ws = (float*)d_ws;
    float* rs = ws;
    float* cs = ws + 1024;
    float* rn = ws + 2048;
    float* cm = ws + 12288;
    float* Wn = ws + 24576;
    float* out = (float*)d_out;

    k_sums<<<1024, 256, 0, stream>>>(W, rs, cs);
    k_tables<<<8, 256, 0, stream>>>(rs, cs, W1, b1, rn, cm);
    k_newweight<<<4096, 256, 0, stream>>>(W, rn, cm, W1, W2, b2, W3, b3, Wn);
    k_gemm<<<dim3(16, 32), 256, 0, stream>>>(X, Wn, out);
    k_softmax<<<4096, 256, 0, stream>>>(out);
}

// Round 2
// 212.039 us; speedup vs baseline: 1.3614x; 1.3614x over previous
//
#include <hip/hip_runtime.h>
#include <hip/hip_bf16.h>
#include <stdint.h>

// Problem: X[4096,1024] f32; weight[1024,1024]; tiny MLP params.
// out = softmax(relu(X @ new_weight)), new_weight = weight + MLP(feat)[...,0].
// hidden-tensor features collapse analytically to bit features of (n,m);
// layer-1 is rank-1 + separable -> per-row table rn[n][10] + per-col table cm[m][10].
//
// GEMM path: 3-term bf16 split (xh*wh + xl*wh + xh*wl) with MFMA 16x16x32.
//
// ws layout:
//   floats: rs[1024] @0, cs[1024] @1024, rn[10240] @2048, cm[10240] @12288
//   bytes:  Bt (bf16 [1024][2048], hi|lo)  @ 98304            (4 MB)
//           Ah (bf16 [4096][1024])         @ 98304+4 MB       (8 MB)
//           Al (bf16 [4096][1024])         @ 98304+12 MB      (8 MB)
// total NEED = 21069824 bytes; f32 fallback path if ws_size smaller.

typedef __attribute__((ext_vector_type(8))) short bf16x8;
typedef __attribute__((ext_vector_type(4))) float f32x4;

__device__ __forceinline__ unsigned short f2bf_rn(float x) {
    unsigned u = __float_as_uint(x);
    return (unsigned short)((u + 0x7fffu + ((u >> 16) & 1u)) >> 16);
}
__device__ __forceinline__ float bf2f(unsigned short h) {
    return __uint_as_float(((unsigned)h) << 16);
}
__device__ __forceinline__ void gld16(const void* g, void* l) {
    __builtin_amdgcn_global_load_lds(
        (const __attribute__((address_space(1))) unsigned*)g,
        (__attribute__((address_space(3))) unsigned*)l, 16, 0, 0);
}

// ---------------------------------------------------------------------------
// Row sums (wave-per-row, shuffle reduce) + col sums (block partial + atomic).
// cs must be zeroed before launch (hipMemsetAsync).
__global__ __launch_bounds__(256) void k_sums2(const float* __restrict__ w,
                                               float* __restrict__ rs,
                                               float* __restrict__ cs) {
    __shared__ float part[4][1024];
    int t = threadIdx.x, lane = t & 63, wv = t >> 6;
    int row = blockIdx.x * 4 + wv;
    float rsum = 0.f;
    #pragma unroll
    for (int j = 0; j < 16; ++j) {
        float v = w[(size_t)row * 1024 + j * 64 + lane];
        part[wv][j * 64 + lane] = v;
        rsum += v;
    }
    #pragma unroll
    for (int o = 32; o; o >>= 1) rsum += __shfl_down(rsum, o);
    if (lane == 0) rs[row] = rsum;
    __syncthreads();
    #pragma unroll
    for (int j = 0; j < 4; ++j) {
        int c = t + j * 256;
        atomicAdd(&cs[c], part[0][c] + part[1][c] + part[2][c] + part[3][c]);
    }
}

// ---------------------------------------------------------------------------
// Per-row (rn) and per-col (cm) layer-1 tables (analytic hidden collapse).
__global__ void k_tables(const float* __restrict__ rs, const float* __restrict__ cs,
                         const float* __restrict__ W1, const float* __restrict__ b1,
                         float* __restrict__ rn, float* __restrict__ cm) {
    int id = blockIdx.x * 256 + threadIdx.x;
    if (id >= 2048) return;
    int n = id & 1023;
    int side = id >> 10;
    const float inv = 1.0f / 1023.0f;
    if (side == 0) {
        float r = rs[n];
        for (int h = 0; h < 10; h++) {
            float v = r * W1[2 * 10 + h] * inv;
            for (int j = 0; j < 10; j++) {
                float bit = (float)((n >> (9 - j)) & 1);
                v += bit * (W1[(3 + j) * 10 + h] + W1[(43 + j) * 10 + h]
                            - W1[(23 + j) * 10 + h] * inv);
                v += (512.0f * inv) * W1[(23 + j) * 10 + h];
            }
            rn[n * 10 + h] = v;
        }
    } else {
        float c = cs[n];
        for (int h = 0; h < 10; h++) {
            float v = c * W1[1 * 10 + h] * inv + b1[h];
            for (int j = 0; j < 10; j++) {
                float bit = (float)((n >> (9 - j)) & 1);
                v += bit * (W1[(13 + j) * 10 + h] + W1[(33 + j) * 10 + h]
                            - W1[(53 + j) * 10 + h] * inv);
                v += (512.0f * inv) * W1[(53 + j) * 10 + h];
            }
            cm[n * 10 + h] = v;
        }
    }
}

// ---------------------------------------------------------------------------
// new_weight MLP on 32x32 tiles; writes TRANSPOSED bf16 hi/lo to Bt[m][k]:
// Bt[m][n] = bf16_hi(Wn[n][m]), Bt[m][1024+n] = bf16_lo(Wn[n][m]).
__global__ __launch_bounds__(256) void k_nw(const float* __restrict__ w,
        const float* __restrict__ rn, const float* __restrict__ cm,
        const float* __restrict__ W1, const float* __restrict__ W2,
        const float* __restrict__ b2, const float* __restrict__ W3,
        const float* __restrict__ b3, unsigned short* __restrict__ Bt) {
    __shared__ float sW2[100], sb2[10], sw3[10], sa[10];
    __shared__ float s_rn[320], s_cm[320];
    __shared__ float st[32][33];   // +1 pad: conflict-free column reads
    int t = threadIdx.x;
    int n0 = blockIdx.x * 32;      // weight-row base (k of gemm)
    int m0 = blockIdx.y * 32;      // weight-col base (n of gemm)
    for (int i = t; i < 320; i += 256) { s_rn[i] = rn[n0 * 10 + i]; s_cm[i] = cm[m0 * 10 + i]; }
    if (t < 100) sW2[t] = W2[t];
    if (t < 10) {
        sb2[t] = b2[t];
        sw3[t] = W3[t * 21];                     // W3[:,0], row stride 21
        sa[t]  = W1[t] - (W1[10 + t] + W1[20 + t]) * (1.0f / 1023.0f);
    }
    float b30 = b3[0];
    __syncthreads();
    int ml = t & 31;
    #pragma unroll
    for (int i = 0; i < 4; i++) {
        int nl = (t >> 5) + 8 * i;
        float wv = w[(size_t)(n0 + nl) * 1024 + m0 + ml];
        float h1[10];
        #pragma unroll
        for (int h = 0; h < 10; h++)
            h1[h] = fmaxf(wv * sa[h] + s_rn[nl * 10 + h] + s_cm[ml * 10 + h], 0.f);
        float u = b30;
        #pragma unroll
        for (int k = 0; k < 10; k++) {
            float h2 = sb2[k];
            #pragma unroll
            for (int h = 0; h < 10; h++) h2 += h1[h] * sW2[h * 10 + k];
            u += fmaxf(h2, 0.f) * sw3[k];
        }
        st[nl][ml] = wv + u;
    }
    __syncthreads();
    int mrow = t >> 3, kc = t & 7;
    unsigned short hi4[4], lo4[4];
    #pragma unroll
    for (int j = 0; j < 4; j++) {
        float v = st[kc * 4 + j][mrow];
        unsigned short h = f2bf_rn(v);
        hi4[j] = h;
        lo4[j] = f2bf_rn(v - bf2f(h));
    }
    size_t base = (size_t)(m0 + mrow) * 2048 + n0 + kc * 4;
    *(ushort4*)&Bt[base]        = make_ushort4(hi4[0], hi4[1], hi4[2], hi4[3]);
    *(ushort4*)&Bt[base + 1024] = make_ushort4(lo4[0], lo4[1], lo4[2], lo4[3]);
}

// ---------------------------------------------------------------------------
// Split X -> Ah (bf16 hi) + Al (bf16 lo of remainder).
__global__ __launch_bounds__(256) void k_convX(const float* __restrict__ X,
        unsigned short* __restrict__ Ah, unsigned short* __restrict__ Al) {
    size_t idx = ((size_t)blockIdx.x * 256 + threadIdx.x) * 4;
    float4 v = *(const float4*)&X[idx];
    ushort4 h, l;
    h.x = f2bf_rn(v.x); l.x = f2bf_rn(v.x - bf2f(h.x));
    h.y = f2bf_rn(v.y); l.y = f2bf_rn(v.y - bf2f(h.y));
    h.z = f2bf_rn(v.z); l.z = f2bf_rn(v.z - bf2f(h.z));
    h.w = f2bf_rn(v.w); l.w = f2bf_rn(v.w - bf2f(h.w));
    *(ushort4*)&Ah[idx] = h;
    *(ushort4*)&Al[idx] = l;
}

// ---------------------------------------------------------------------------
// C = relu(X @ Wn) via 3-phase bf16 MFMA. Block 128x128, 4 waves, 64x64/wave,
// 4x4 of mfma_f32_16x16x32_bf16, BK=64. XOR-swizzled LDS chunks: chunk (row,seg)
// stored at position row*8 + (seg ^ (row&7)) -> frag reads spread over all
// bank-quads (2-way = free) while global_load_lds stays lane-contiguous.
__global__ __launch_bounds__(256, 1) void k_gemm3(const unsigned short* __restrict__ Ah,
        const unsigned short* __restrict__ Al, const unsigned short* __restrict__ Bt,
        float* __restrict__ out) {
    __shared__ unsigned short sAh[128 * 64], sAl[128 * 64];
    __shared__ unsigned short sBh[128 * 64], sBl[128 * 64];
    int tid = threadIdx.x;
    int lane = tid & 63, w = tid >> 6;
    int n0 = blockIdx.x * 128, m0 = blockIdx.y * 128;
    int wm = (w >> 1) * 64, wn = (w & 1) * 64;
    int quad = lane >> 4, l16 = lane & 15;

    f32x4 acc[4][4];
    #pragma unroll
    for (int i = 0; i < 4; i++)
        #pragma unroll
        for (int j = 0; j < 4; j++) acc[i][j] = (f32x4)0.f;

    for (int it = 0; it < 16; ++it) {
        int kb = it * 64;
        __syncthreads();
        #pragma unroll
        for (int s = 0; s < 4; ++s) {
            int P = s * 256 + tid;
            int row = P >> 3;
            int seg = (P & 7) ^ (row & 7);
            int ldsOff = (s * 256 + w * 64) * 8;        // wave-uniform dst
            size_t ga = (size_t)(m0 + row) * 1024 + kb + seg * 8;
            size_t gb = (size_t)(n0 + row) * 2048 + kb + seg * 8;
            gld16(&Ah[ga], &sAh[ldsOff]);
            gld16(&Al[ga], &sAl[ldsOff]);
            gld16(&Bt[gb], &sBh[ldsOff]);
            gld16(&Bt[gb + 1024], &sBl[ldsOff]);
        }
        __syncthreads();
        #pragma unroll
        for (int ks = 0; ks < 2; ++ks) {
            int segk = ks * 4 + quad;
            bf16x8 ah[4], al[4], bh[4], bl[4];
            #pragma unroll
            for (int i = 0; i < 4; ++i) {
                int ra = wm + i * 16 + l16;
                int ca = (ra * 8 + (segk ^ (ra & 7))) * 8;
                ah[i] = *(const bf16x8*)&sAh[ca];
                al[i] = *(const bf16x8*)&sAl[ca];
                int rb = wn + i * 16 + l16;
                int cb = (rb * 8 + (segk ^ (rb & 7))) * 8;
                bh[i] = *(const bf16x8*)&sBh[cb];
                bl[i] = *(const bf16x8*)&sBl[cb];
            }
            #pragma unroll
            for (int i = 0; i < 4; ++i)
                #pragma unroll
                for (int j = 0; j < 4; ++j) {
                    acc[i][j] = __builtin_amdgcn_mfma_f32_16x16x32_bf16(ah[i], bh[j], acc[i][j], 0, 0, 0);
                    acc[i][j] = __builtin_amdgcn_mfma_f32_16x16x32_bf16(al[i], bh[j], acc[i][j], 0, 0, 0);
                    acc[i][j] = __builtin_amdgcn_mfma_f32_16x16x32_bf16(ah[i], bl[j], acc[i][j], 0, 0, 0);
                }
        }
    }
    // C/D layout: col = lane&15, row = quad*4 + reg  [measured m89/m91]
    #pragma unroll
    for (int i = 0; i < 4; ++i) {
        int mr = m0 + wm + i * 16 + quad * 4;
        #pragma unroll
        for (int j = 0; j < 4; ++j) {
            int nc = n0 + wn + j * 16 + l16;
            #pragma unroll
            for (int r = 0; r < 4; ++r)
                out[(size_t)(mr + r) * 1024 + nc] = fmaxf(acc[i][j][r], 0.f);
        }
    }
}

// ---------------------------------------------------------------------------
// In-place row softmax, shuffle-based (2 barriers).
__global__ __launch_bounds__(256) void k_softmax2(float* __restrict__ C) {
    int row = blockIdx.x, t = threadIdx.x, lane = t & 63, wv = t >> 6;
    __shared__ float red[8];
    float4 v = *(float4*)&C[(size_t)row * 1024 + t * 4];
    float lm = fmaxf(fmaxf(v.x, v.y), fmaxf(v.z, v.w));
    #pragma unroll
    for (int o = 32; o; o >>= 1) lm = fmaxf(lm, __shfl_down(lm, o));
    if (lane == 0) red[wv] = lm;
    __syncthreads();
    float mx = fmaxf(fmaxf(red[0], red[1]), fmaxf(red[2], red[3]));
    float4 e;
    e.x = __expf(v.x - mx); e.y = __expf(v.y - mx);
    e.z = __expf(v.z - mx); e.w = __expf(v.w - mx);
    float ls = e.x + e.y + e.z + e.w;
    #pragma unroll
    for (int o = 32; o; o >>= 1) ls += __shfl_down(ls, o);
    if (lane == 0) red[4 + wv] = ls;
    __syncthreads();
    float inv = 1.0f / (red[4] + red[5] + red[6] + red[7]);
    e.x *= inv; e.y *= inv; e.z *= inv; e.w *= inv;
    *(float4*)&C[(size_t)row * 1024 + t * 4] = e;
}

// ---------------------------------------------------------------------------
// Fallback (round-1 proven) kernels if ws_size is too small for bf16 buffers.
__global__ void k_newweight_f(const float* __restrict__ w,
                              const float* __restrict__ rn, const float* __restrict__ cm,
                              const float* __restrict__ W1, const float* __restrict__ W2,
                              const float* __restrict__ b2, const float* __restrict__ W3,
                              const float* __restrict__ b3, float* __restrict__ Wn) {
    __shared__ float sW2[100], sb2[10], sw3[10], sa[10], srn[10];
    int t = threadIdx.x;
    int g = blockIdx.x * 256 + t;
    int n = g >> 10, m = g & 1023;
    if (t < 100) sW2[t] = W2[t];
    if (t >= 128 && t < 138) sb2[t - 128] = b2[t - 128];
    if (t >= 160 && t < 170) sw3[t - 160] = W3[(t - 160) * 21];
    if (t >= 192 && t < 202) {
        int h = t - 192;
        sa[h] = W1[h] - (W1[10 + h] + W1[20 + h]) * (1.0f / 1023.0f);
    }
    if (t >= 224 && t < 234) { int h = t - 224; srn[h] = rn[n * 10 + h]; }
    __syncthreads();
    float wv = w[g];
    float h1[10];
    #pragma unroll
    for (int h = 0; h < 10; h++)
        h1[h] = fmaxf(wv * sa[h] + srn[h] + cm[m * 10 + h], 0.0f);
    float u = b3[0];
    #pragma unroll
    for (int k = 0; k < 10; k++) {
        float h2 = sb2[k];
        #pragma unroll
        for (int h = 0; h < 10; h++) h2 += h1[h] * sW2[h * 10 + k];
        u += fmaxf(h2, 0.0f) * sw3[k];
    }
    Wn[g] = wv + u;
}

__global__ __launch_bounds__(256) void k_gemm_f(const float* __restrict__ A,
                                                const float* __restrict__ B,
                                                float* __restrict__ C) {
    __shared__ float sA[16 * 132];
    __shared__ float sB[16 * 64];
    int tid = threadIdx.x;
    int tx = tid & 15, ty = tid >> 4;
    int n0 = blockIdx.x * 64, m0 = blockIdx.y * 128;
    float acc[8][4];
    #pragma unroll
    for (int i = 0; i < 8; i++)
        #pragma unroll
        for (int j = 0; j < 4; j++) acc[i][j] = 0.f;
    for (int k0 = 0; k0 < 1024; k0 += 16) {
        __syncthreads();
        #pragma unroll
        for (int s = 0; s < 2; s++) {
            int f = tid + 256 * s;
            int row = f >> 2, cseg = f & 3;
            const float4 v = *(const float4*)&A[(m0 + row) * 1024 + k0 + cseg * 4];
            sA[(cseg * 4 + 0) * 132 + row] = v.x;
            sA[(cseg * 4 + 1) * 132 + row] = v.y;
            sA[(cseg * 4 + 2) * 132 + row] = v.z;
            sA[(cseg * 4 + 3) * 132 + row] = v.w;
        }
        {
            int row = tid >> 4, cseg = tid & 15;
            *(float4*)&sB[row * 64 + cseg * 4] =
                *(const float4*)&B[(k0 + row) * 1024 + n0 + cseg * 4];
        }
        __syncthreads();
        #pragma unroll
        for (int kk = 0; kk < 16; kk++) {
            float4 a0 = *(const float4*)&sA[kk * 132 + ty * 8];
            float4 a1 = *(const float4*)&sA[kk * 132 + ty * 8 + 4];
            float4 bv = *(const float4*)&sB[kk * 64 + tx * 4];
            float av[8] = {a0.x, a0.y, a0.z, a0.w, a1.x, a1.y, a1.z, a1.w};
            float bb[4] = {bv.x, bv.y, bv.z, bv.w};
            #pragma unroll
            for (int i = 0; i < 8; i++)
                #pragma unroll
                for (int j = 0; j < 4; j++) acc[i][j] += av[i] * bb[j];
        }
    }
    #pragma unroll
    for (int i = 0; i < 8; i++) {
        float4 r;
        r.x = fmaxf(acc[i][0], 0.f);
        r.y = fmaxf(acc[i][1], 0.f);
        r.z = fmaxf(acc[i][2], 0.f);
        r.w = fmaxf(acc[i][3], 0.f);
        *(float4*)&C[(m0 + ty * 8 + i) * 1024 + n0 + tx * 4] = r;
    }
}

// ---------------------------------------------------------------------------
extern "C" void kernel_launch(void* const* d_in, const int* in_sizes, int n_in,
                              void* d_out, int out_size, void* d_ws, size_t ws_size,
                              hipStream_t stream) {
    const float* X  = (const float*)d_in[0];
    const float* W  = (const float*)d_in[1];
    // d_in[2] = hidden: analytic, never read
    const float* W1 = (const float*)d_in[3];
    const float* b1 = (const float*)d_in[4];
    const float* W2 = (const float*)d_in[5];
    const float* b2 = (const float*)d_in[6];
    const float* W3 = (const float*)d_in[7];
    const float* b3 = (const float*)d_in[8];

    float* ws = (float*)d_ws;
    float* rs = ws;
    float* cs = ws + 1024;
    float* rn = ws + 2048;
    float* cm = ws + 12288;
    float* out = (float*)d_out;

    hipMemsetAsync(cs, 0, 1024 * sizeof(float), stream);
    k_sums2<<<256, 256, 0, stream>>>(W, rs, cs);
    k_tables<<<8, 256, 0, stream>>>(rs, cs, W1, b1, rn, cm);

    const size_t NEED = 98304 + 4194304 + 2 * 8388608;  // 21069824 B
    if (ws_size >= NEED) {
        unsigned short* Bt = (unsigned short*)((char*)d_ws + 98304);
        unsigned short* Ah = (unsigned short*)((char*)d_ws + 98304 + 4194304);
        unsigned short* Al = Ah + (size_t)4096 * 1024;
        k_nw<<<dim3(32, 32), 256, 0, stream>>>(W, rn, cm, W1, W2, b2, W3, b3, Bt);
        k_convX<<<4096, 256, 0, stream>>>(X, Ah, Al);
        k_gemm3<<<dim3(8, 32), 256, 0, stream>>>(Ah, Al, Bt, out);
    } else {
        float* Wn = ws + 24576;
        k_newweight_f<<<4096, 256, 0, stream>>>(W, rn, cm, W1, W2, b2, W3, b3, Wn);
        k_gemm_f<<<dim3(16, 32), 256, 0, stream>>>(X, Wn, out);
    }
    k_softmax2<<<4096, 256, 0, stream>>>(out);
}

// Round 3
// 202.144 us; speedup vs baseline: 1.4280x; 1.0489x over previous
//
#include <hip/hip_runtime.h>
#include <hip/hip_bf16.h>
#include <stdint.h>

// out = softmax(relu(X @ new_weight)), new_weight = weight + MLP(feat)[...,0].
// hidden features collapse analytically to bit features of (n,m); layer-1 is
// rank-1 + separable -> per-row table rn[n][10] + per-col table cm[m][10],
// computed inline per k_nw block (no standalone tables kernel).
// GEMM: 3-term bf16 split (xh*wh + xl*wh + xh*wl) with MFMA 16x16x32.
//
// 4 dispatches total: k_pre (sums + X split) -> k_nw -> k_gemm3 -> k_softmax2.
//
// ws layout (bytes):
//   rs      @ 0        : f32[1024]          row sums of weight
//   cs_part @ 4096     : f32[64][1024]      per-block partial col sums
//   Bt      @ 266240   : bf16[1024][2048]   new_weight^T hi|lo   (4 MB)
//   Ah      @ 4460544  : bf16[4096][1024]   X hi                 (8 MB)
//   Al      @ 12849152 : bf16[4096][1024]   X lo                 (8 MB)

#define RS_OFF      0
#define CSPART_OFF  4096
#define BT_OFF      266240
#define AH_OFF      4460544
#define AL_OFF      12849152

typedef __attribute__((ext_vector_type(8))) short bf16x8;
typedef __attribute__((ext_vector_type(4))) float f32x4;

__device__ __forceinline__ unsigned short f2bf_rn(float x) {
    unsigned u = __float_as_uint(x);
    return (unsigned short)((u + 0x7fffu + ((u >> 16) & 1u)) >> 16);
}
__device__ __forceinline__ float bf2f(unsigned short h) {
    return __uint_as_float(((unsigned)h) << 16);
}
__device__ __forceinline__ void gld16(const void* g, void* l) {
    __builtin_amdgcn_global_load_lds(
        (const __attribute__((address_space(1))) unsigned*)g,
        (__attribute__((address_space(3))) unsigned*)l, 16, 0, 0);
}

// ---------------------------------------------------------------------------
// K1: fused. Blocks 0..63: row sums (wave per 4 rows, shuffle) + 64 partial
// colsum vectors (no atomics, no memset). Blocks 64..1087: split X -> Ah/Al.
__global__ __launch_bounds__(256) void k_pre(const float* __restrict__ w,
        const float* __restrict__ X, float* __restrict__ rs,
        float* __restrict__ cs_part,
        unsigned short* __restrict__ Ah, unsigned short* __restrict__ Al) {
    int t = threadIdx.x;
    if (blockIdx.x < 64) {
        __shared__ float part[4][1024];
        int lane = t & 63, wv = t >> 6;
        int r0 = blockIdx.x * 16 + wv * 4;
        float ccol[16];
        #pragma unroll
        for (int j = 0; j < 16; ++j) ccol[j] = 0.f;
        #pragma unroll
        for (int rr = 0; rr < 4; ++rr) {
            int row = r0 + rr;
            float rsum = 0.f;
            #pragma unroll
            for (int j = 0; j < 16; ++j) {
                float v = w[(size_t)row * 1024 + j * 64 + lane];
                ccol[j] += v;
                rsum += v;
            }
            #pragma unroll
            for (int o = 32; o; o >>= 1) rsum += __shfl_down(rsum, o);
            if (lane == 0) rs[row] = rsum;
        }
        #pragma unroll
        for (int j = 0; j < 16; ++j) part[wv][j * 64 + lane] = ccol[j];
        __syncthreads();
        #pragma unroll
        for (int j = 0; j < 4; ++j) {
            int c = t + j * 256;
            cs_part[(size_t)blockIdx.x * 1024 + c] =
                part[0][c] + part[1][c] + part[2][c] + part[3][c];
        }
    } else {
        int b2 = blockIdx.x - 64;           // 0..1023, 4096 floats each
        #pragma unroll
        for (int p = 0; p < 4; ++p) {
            size_t idx = (size_t)b2 * 4096 + p * 1024 + t * 4;
            float4 v = *(const float4*)&X[idx];
            ushort4 h, l;
            h.x = f2bf_rn(v.x); l.x = f2bf_rn(v.x - bf2f(h.x));
            h.y = f2bf_rn(v.y); l.y = f2bf_rn(v.y - bf2f(h.y));
            h.z = f2bf_rn(v.z); l.z = f2bf_rn(v.z - bf2f(h.z));
            h.w = f2bf_rn(v.w); l.w = f2bf_rn(v.w - bf2f(h.w));
            *(ushort4*)&Ah[idx] = h;
            *(ushort4*)&Al[idx] = l;
        }
    }
}

// ---------------------------------------------------------------------------
// K2: new_weight MLP on 32x32 tiles with inline rn/cm tables and inline
// colsum reduction. Writes TRANSPOSED bf16 hi/lo: Bt[m][n]=hi, Bt[m][1024+n]=lo.
__global__ __launch_bounds__(256) void k_nw(const float* __restrict__ w,
        const float* __restrict__ rs, const float* __restrict__ cs_part,
        const float* __restrict__ W1, const float* __restrict__ b1,
        const float* __restrict__ W2, const float* __restrict__ b2,
        const float* __restrict__ W3, const float* __restrict__ b3,
        unsigned short* __restrict__ Bt) {
    __shared__ float sW1[630], sW2[100], sb1[10], sb2[10], sw3[10], sa[10];
    __shared__ float rs_loc[32], cs_loc[32];
    __shared__ float rn_loc[320], cm_loc[320];
    __shared__ float st[32][33];   // +1 pad: conflict-free column reads
    int t = threadIdx.x;
    int n0 = blockIdx.x * 32;      // weight-row base (k of gemm)
    int m0 = blockIdx.y * 32;      // weight-col base (n of gemm)
    const float inv = 1.0f / 1023.0f;

    for (int i = t; i < 630; i += 256) sW1[i] = W1[i];
    if (t < 100) sW2[t] = W2[t];
    if (t >= 128 && t < 138) { sb1[t - 128] = b1[t - 128]; sb2[t - 128] = b2[t - 128]; }
    if (t >= 160 && t < 170) sw3[t - 160] = W3[(t - 160) * 21];  // W3[:,0]
    if (t >= 192 && t < 224) rs_loc[t - 192] = rs[n0 + t - 192];
    if (t >= 224 && t < 256) {
        float s = 0.f;
        #pragma unroll
        for (int p = 0; p < 64; ++p) s += cs_part[(size_t)p * 1024 + m0 + (t - 224)];
        cs_loc[t - 224] = s;
    }
    float b30 = b3[0];
    __syncthreads();
    if (t < 10) sa[t] = sW1[t] - (sW1[10 + t] + sW1[20 + t]) * inv;
    // rn/cm tables for this block's 32 rows / 32 cols (640 values)
    for (int id = t; id < 640; id += 256) {
        int h = id % 10, i = (id / 10) & 31, side = id >= 320;
        if (!side) {
            int n = n0 + i;
            float v = rs_loc[i] * sW1[20 + h] * inv;
            #pragma unroll
            for (int j = 0; j < 10; j++) {
                float bit = (float)((n >> (9 - j)) & 1);
                v += bit * (sW1[(3 + j) * 10 + h] + sW1[(43 + j) * 10 + h]
                            - sW1[(23 + j) * 10 + h] * inv);
                v += (512.0f * inv) * sW1[(23 + j) * 10 + h];
            }
            rn_loc[i * 10 + h] = v;
        } else {
            int m = m0 + i;
            float v = cs_loc[i] * sW1[10 + h] * inv + sb1[h];
            #pragma unroll
            for (int j = 0; j < 10; j++) {
                float bit = (float)((m >> (9 - j)) & 1);
                v += bit * (sW1[(13 + j) * 10 + h] + sW1[(33 + j) * 10 + h]
                            - sW1[(53 + j) * 10 + h] * inv);
                v += (512.0f * inv) * sW1[(53 + j) * 10 + h];
            }
            cm_loc[i * 10 + h] = v;
        }
    }
    __syncthreads();
    int ml = t & 31;
    #pragma unroll
    for (int i = 0; i < 4; i++) {
        int nl = (t >> 5) + 8 * i;
        float wv = w[(size_t)(n0 + nl) * 1024 + m0 + ml];
        float h1[10];
        #pragma unroll
        for (int h = 0; h < 10; h++)
            h1[h] = fmaxf(wv * sa[h] + rn_loc[nl * 10 + h] + cm_loc[ml * 10 + h], 0.f);
        float u = b30;
        #pragma unroll
        for (int k = 0; k < 10; k++) {
            float h2 = sb2[k];
            #pragma unroll
            for (int h = 0; h < 10; h++) h2 += h1[h] * sW2[h * 10 + k];
            u += fmaxf(h2, 0.f) * sw3[k];
        }
        st[nl][ml] = wv + u;
    }
    __syncthreads();
    int mrow = t >> 3, kc = t & 7;
    unsigned short hi4[4], lo4[4];
    #pragma unroll
    for (int j = 0; j < 4; j++) {
        float v = st[kc * 4 + j][mrow];
        unsigned short h = f2bf_rn(v);
        hi4[j] = h;
        lo4[j] = f2bf_rn(v - bf2f(h));
    }
    size_t base = (size_t)(m0 + mrow) * 2048 + n0 + kc * 4;
    *(ushort4*)&Bt[base]        = make_ushort4(hi4[0], hi4[1], hi4[2], hi4[3]);
    *(ushort4*)&Bt[base + 1024] = make_ushort4(lo4[0], lo4[1], lo4[2], lo4[3]);
}

// ---------------------------------------------------------------------------
// K3: C = relu(X @ Wn) via 3-phase bf16 MFMA. Block 128x128, 4 waves,
// 64x64/wave, 4x4 of mfma_f32_16x16x32_bf16, BK=64. XOR-swizzled LDS chunks
// (pos = row*8 + (seg ^ (row&7))): staging stays lane-contiguous for
// global_load_lds, frag reads spread over all bank-quads (2-way = free).
// [unchanged from round 2 — proven correct, absmax 9.8e-4]
__global__ __launch_bounds__(256, 1) void k_gemm3(const unsigned short* __restrict__ Ah,
        const unsigned short* __restrict__ Al, const unsigned short* __restrict__ Bt,
        float* __restrict__ out) {
    __shared__ unsigned short sAh[128 * 64], sAl[128 * 64];
    __shared__ unsigned short sBh[128 * 64], sBl[128 * 64];
    int tid = threadIdx.x;
    int lane = tid & 63, w = tid >> 6;
    int n0 = blockIdx.x * 128, m0 = blockIdx.y * 128;
    int wm = (w >> 1) * 64, wn = (w & 1) * 64;
    int quad = lane >> 4, l16 = lane & 15;

    f32x4 acc[4][4];
    #pragma unroll
    for (int i = 0; i < 4; i++)
        #pragma unroll
        for (int j = 0; j < 4; j++) acc[i][j] = (f32x4)0.f;

    for (int it = 0; it < 16; ++it) {
        int kb = it * 64;
        __syncthreads();
        #pragma unroll
        for (int s = 0; s < 4; ++s) {
            int P = s * 256 + tid;
            int row = P >> 3;
            int seg = (P & 7) ^ (row & 7);
            int ldsOff = (s * 256 + w * 64) * 8;        // wave-uniform dst
            size_t ga = (size_t)(m0 + row) * 1024 + kb + seg * 8;
            size_t gb = (size_t)(n0 + row) * 2048 + kb + seg * 8;
            gld16(&Ah[ga], &sAh[ldsOff]);
            gld16(&Al[ga], &sAl[ldsOff]);
            gld16(&Bt[gb], &sBh[ldsOff]);
            gld16(&Bt[gb + 1024], &sBl[ldsOff]);
        }
        __syncthreads();
        #pragma unroll
        for (int ks = 0; ks < 2; ++ks) {
            int segk = ks * 4 + quad;
            bf16x8 ah[4], al[4], bh[4], bl[4];
            #pragma unroll
            for (int i = 0; i < 4; ++i) {
                int ra = wm + i * 16 + l16;
                int ca = (ra * 8 + (segk ^ (ra & 7))) * 8;
                ah[i] = *(const bf16x8*)&sAh[ca];
                al[i] = *(const bf16x8*)&sAl[ca];
                int rb = wn + i * 16 + l16;
                int cb = (rb * 8 + (segk ^ (rb & 7))) * 8;
                bh[i] = *(const bf16x8*)&sBh[cb];
                bl[i] = *(const bf16x8*)&sBl[cb];
            }
            #pragma unroll
            for (int i = 0; i < 4; ++i)
                #pragma unroll
                for (int j = 0; j < 4; ++j) {
                    acc[i][j] = __builtin_amdgcn_mfma_f32_16x16x32_bf16(ah[i], bh[j], acc[i][j], 0, 0, 0);
                    acc[i][j] = __builtin_amdgcn_mfma_f32_16x16x32_bf16(al[i], bh[j], acc[i][j], 0, 0, 0);
                    acc[i][j] = __builtin_amdgcn_mfma_f32_16x16x32_bf16(ah[i], bl[j], acc[i][j], 0, 0, 0);
                }
        }
    }
    // C/D layout: col = lane&15, row = quad*4 + reg  [measured m89/m91]
    #pragma unroll
    for (int i = 0; i < 4; ++i) {
        int mr = m0 + wm + i * 16 + quad * 4;
        #pragma unroll
        for (int j = 0; j < 4; ++j) {
            int nc = n0 + wn + j * 16 + l16;
            #pragma unroll
            for (int r = 0; r < 4; ++r)
                out[(size_t)(mr + r) * 1024 + nc] = fmaxf(acc[i][j][r], 0.f);
        }
    }
}

// ---------------------------------------------------------------------------
// K4: in-place row softmax, shuffle-based (2 barriers). [unchanged]
__global__ __launch_bounds__(256) void k_softmax2(float* __restrict__ C) {
    int row = blockIdx.x, t = threadIdx.x, lane = t & 63, wv = t >> 6;
    __shared__ float red[8];
    float4 v = *(float4*)&C[(size_t)row * 1024 + t * 4];
    float lm = fmaxf(fmaxf(v.x, v.y), fmaxf(v.z, v.w));
    #pragma unroll
    for (int o = 32; o; o >>= 1) lm = fmaxf(lm, __shfl_down(lm, o));
    if (lane == 0) red[wv] = lm;
    __syncthreads();
    float mx = fmaxf(fmaxf(red[0], red[1]), fmaxf(red[2], red[3]));
    float4 e;
    e.x = __expf(v.x - mx); e.y = __expf(v.y - mx);
    e.z = __expf(v.z - mx); e.w = __expf(v.w - mx);
    float ls = e.x + e.y + e.z + e.w;
    #pragma unroll
    for (int o = 32; o; o >>= 1) ls += __shfl_down(ls, o);
    if (lane == 0) red[4 + wv] = ls;
    __syncthreads();
    float inv = 1.0f / (red[4] + red[5] + red[6] + red[7]);
    e.x *= inv; e.y *= inv; e.z *= inv; e.w *= inv;
    *(float4*)&C[(size_t)row * 1024 + t * 4] = e;
}

// ---------------------------------------------------------------------------
extern "C" void kernel_launch(void* const* d_in, const int* in_sizes, int n_in,
                              void* d_out, int out_size, void* d_ws, size_t ws_size,
                              hipStream_t stream) {
    const float* X  = (const float*)d_in[0];
    const float* W  = (const float*)d_in[1];
    // d_in[2] = hidden: analytic, never read
    const float* W1 = (const float*)d_in[3];
    const float* b1 = (const float*)d_in[4];
    const float* W2 = (const float*)d_in[5];
    const float* b2 = (const float*)d_in[6];
    const float* W3 = (const float*)d_in[7];
    const float* b3 = (const float*)d_in[8];

    char* wsb = (char*)d_ws;
    float* rs            = (float*)(wsb + RS_OFF);
    float* cs_part       = (float*)(wsb + CSPART_OFF);
    unsigned short* Bt   = (unsigned short*)(wsb + BT_OFF);
    unsigned short* Ah   = (unsigned short*)(wsb + AH_OFF);
    unsigned short* Al   = (unsigned short*)(wsb + AL_OFF);
    float* out = (float*)d_out;

    k_pre<<<1088, 256, 0, stream>>>(W, X, rs, cs_part, Ah, Al);
    k_nw<<<dim3(32, 32), 256, 0, stream>>>(W, rs, cs_part, W1, b1, W2, b2, W3, b3, Bt);
    k_gemm3<<<dim3(8, 32), 256, 0, stream>>>(Ah, Al, Bt, out);
    k_softmax2<<<4096, 256, 0, stream>>>(out);
}

// Round 4
// 190.571 us; speedup vs baseline: 1.5148x; 1.0607x over previous
//
#include <hip/hip_runtime.h>
#include <hip/hip_bf16.h>
#include <stdint.h>

// out = softmax(relu(X @ new_weight)), new_weight = weight + MLP(feat)[...,0].
// hidden features collapse analytically to bit features of (n,m); layer-1 is
// rank-1 + separable -> per-row table rn[n][10] + per-col table cm[m][10],
// computed inline per k_nw block.
// GEMM: 3-term bf16 split (xh*wh + xl*wh + xh*wl) with MFMA 16x16x32.
// R4 change: gemm tile 128x128 -> 128x64 (grid 256 -> 512 blocks = 2 blocks/CU,
// LDS 64 KB -> 48 KB) to get barrier-drain overlap between co-resident blocks.
//
// 4 dispatches: k_pre (sums + X split) -> k_nw -> k_gemm4 -> k_softmax2.
//
// ws layout (bytes):
//   rs      @ 0        : f32[1024]          row sums of weight
//   cs_part @ 4096     : f32[64][1024]      per-block partial col sums
//   Bt      @ 266240   : bf16[1024][2048]   new_weight^T hi|lo   (4 MB)
//   Ah      @ 4460544  : bf16[4096][1024]   X hi                 (8 MB)
//   Al      @ 12849152 : bf16[4096][1024]   X lo                 (8 MB)

#define RS_OFF      0
#define CSPART_OFF  4096
#define BT_OFF      266240
#define AH_OFF      4460544
#define AL_OFF      12849152

typedef __attribute__((ext_vector_type(8))) short bf16x8;
typedef __attribute__((ext_vector_type(4))) float f32x4;

__device__ __forceinline__ unsigned short f2bf_rn(float x) {
    unsigned u = __float_as_uint(x);
    return (unsigned short)((u + 0x7fffu + ((u >> 16) & 1u)) >> 16);
}
__device__ __forceinline__ float bf2f(unsigned short h) {
    return __uint_as_float(((unsigned)h) << 16);
}
__device__ __forceinline__ void gld16(const void* g, void* l) {
    __builtin_amdgcn_global_load_lds(
        (const __attribute__((address_space(1))) unsigned*)g,
        (__attribute__((address_space(3))) unsigned*)l, 16, 0, 0);
}

// ---------------------------------------------------------------------------
// K1: fused. Blocks 0..63: row sums (wave per 4 rows, shuffle) + 64 partial
// colsum vectors (no atomics, no memset). Blocks 64..1087: split X -> Ah/Al.
__global__ __launch_bounds__(256) void k_pre(const float* __restrict__ w,
        const float* __restrict__ X, float* __restrict__ rs,
        float* __restrict__ cs_part,
        unsigned short* __restrict__ Ah, unsigned short* __restrict__ Al) {
    int t = threadIdx.x;
    if (blockIdx.x < 64) {
        __shared__ float part[4][1024];
        int lane = t & 63, wv = t >> 6;
        int r0 = blockIdx.x * 16 + wv * 4;
        float ccol[16];
        #pragma unroll
        for (int j = 0; j < 16; ++j) ccol[j] = 0.f;
        #pragma unroll
        for (int rr = 0; rr < 4; ++rr) {
            int row = r0 + rr;
            float rsum = 0.f;
            #pragma unroll
            for (int j = 0; j < 16; ++j) {
                float v = w[(size_t)row * 1024 + j * 64 + lane];
                ccol[j] += v;
                rsum += v;
            }
            #pragma unroll
            for (int o = 32; o; o >>= 1) rsum += __shfl_down(rsum, o);
            if (lane == 0) rs[row] = rsum;
        }
        #pragma unroll
        for (int j = 0; j < 16; ++j) part[wv][j * 64 + lane] = ccol[j];
        __syncthreads();
        #pragma unroll
        for (int j = 0; j < 4; ++j) {
            int c = t + j * 256;
            cs_part[(size_t)blockIdx.x * 1024 + c] =
                part[0][c] + part[1][c] + part[2][c] + part[3][c];
        }
    } else {
        int b2 = blockIdx.x - 64;           // 0..1023, 4096 floats each
        #pragma unroll
        for (int p = 0; p < 4; ++p) {
            size_t idx = (size_t)b2 * 4096 + p * 1024 + t * 4;
            float4 v = *(const float4*)&X[idx];
            ushort4 h, l;
            h.x = f2bf_rn(v.x); l.x = f2bf_rn(v.x - bf2f(h.x));
            h.y = f2bf_rn(v.y); l.y = f2bf_rn(v.y - bf2f(h.y));
            h.z = f2bf_rn(v.z); l.z = f2bf_rn(v.z - bf2f(h.z));
            h.w = f2bf_rn(v.w); l.w = f2bf_rn(v.w - bf2f(h.w));
            *(ushort4*)&Ah[idx] = h;
            *(ushort4*)&Al[idx] = l;
        }
    }
}

// ---------------------------------------------------------------------------
// K2: new_weight MLP on 32x32 tiles with inline rn/cm tables and inline
// colsum reduction. Writes TRANSPOSED bf16 hi/lo: Bt[m][n]=hi, Bt[m][1024+n]=lo.
__global__ __launch_bounds__(256) void k_nw(const float* __restrict__ w,
        const float* __restrict__ rs, const float* __restrict__ cs_part,
        const float* __restrict__ W1, const float* __restrict__ b1,
        const float* __restrict__ W2, const float* __restrict__ b2,
        const float* __restrict__ W3, const float* __restrict__ b3,
        unsigned short* __restrict__ Bt) {
    __shared__ float sW1[630], sW2[100], sb1[10], sb2[10], sw3[10], sa[10];
    __shared__ float rs_loc[32], cs_loc[32];
    __shared__ float rn_loc[320], cm_loc[320];
    __shared__ float st[32][33];   // +1 pad: conflict-free column reads
    int t = threadIdx.x;
    int n0 = blockIdx.x * 32;      // weight-row base (k of gemm)
    int m0 = blockIdx.y * 32;      // weight-col base (n of gemm)
    const float inv = 1.0f / 1023.0f;

    for (int i = t; i < 630; i += 256) sW1[i] = W1[i];
    if (t < 100) sW2[t] = W2[t];
    if (t >= 128 && t < 138) { sb1[t - 128] = b1[t - 128]; sb2[t - 128] = b2[t - 128]; }
    if (t >= 160 && t < 170) sw3[t - 160] = W3[(t - 160) * 21];  // W3[:,0]
    if (t >= 192 && t < 224) rs_loc[t - 192] = rs[n0 + t - 192];
    if (t >= 224 && t < 256) {
        float s = 0.f;
        #pragma unroll
        for (int p = 0; p < 64; ++p) s += cs_part[(size_t)p * 1024 + m0 + (t - 224)];
        cs_loc[t - 224] = s;
    }
    float b30 = b3[0];
    __syncthreads();
    if (t < 10) sa[t] = sW1[t] - (sW1[10 + t] + sW1[20 + t]) * inv;
    // rn/cm tables for this block's 32 rows / 32 cols (640 values)
    for (int id = t; id < 640; id += 256) {
        int h = id % 10, i = (id / 10) & 31, side = id >= 320;
        if (!side) {
            int n = n0 + i;
            float v = rs_loc[i] * sW1[20 + h] * inv;
            #pragma unroll
            for (int j = 0; j < 10; j++) {
                float bit = (float)((n >> (9 - j)) & 1);
                v += bit * (sW1[(3 + j) * 10 + h] + sW1[(43 + j) * 10 + h]
                            - sW1[(23 + j) * 10 + h] * inv);
                v += (512.0f * inv) * sW1[(23 + j) * 10 + h];
            }
            rn_loc[i * 10 + h] = v;
        } else {
            int m = m0 + i;
            float v = cs_loc[i] * sW1[10 + h] * inv + sb1[h];
            #pragma unroll
            for (int j = 0; j < 10; j++) {
                float bit = (float)((m >> (9 - j)) & 1);
                v += bit * (sW1[(13 + j) * 10 + h] + sW1[(33 + j) * 10 + h]
                            - sW1[(53 + j) * 10 + h] * inv);
                v += (512.0f * inv) * sW1[(53 + j) * 10 + h];
            }
            cm_loc[i * 10 + h] = v;
        }
    }
    __syncthreads();
    int ml = t & 31;
    #pragma unroll
    for (int i = 0; i < 4; i++) {
        int nl = (t >> 5) + 8 * i;
        float wv = w[(size_t)(n0 + nl) * 1024 + m0 + ml];
        float h1[10];
        #pragma unroll
        for (int h = 0; h < 10; h++)
            h1[h] = fmaxf(wv * sa[h] + rn_loc[nl * 10 + h] + cm_loc[ml * 10 + h], 0.f);
        float u = b30;
        #pragma unroll
        for (int k = 0; k < 10; k++) {
            float h2 = sb2[k];
            #pragma unroll
            for (int h = 0; h < 10; h++) h2 += h1[h] * sW2[h * 10 + k];
            u += fmaxf(h2, 0.f) * sw3[k];
        }
        st[nl][ml] = wv + u;
    }
    __syncthreads();
    int mrow = t >> 3, kc = t & 7;
    unsigned short hi4[4], lo4[4];
    #pragma unroll
    for (int j = 0; j < 4; j++) {
        float v = st[kc * 4 + j][mrow];
        unsigned short h = f2bf_rn(v);
        hi4[j] = h;
        lo4[j] = f2bf_rn(v - bf2f(h));
    }
    size_t base = (size_t)(m0 + mrow) * 2048 + n0 + kc * 4;
    *(ushort4*)&Bt[base]        = make_ushort4(hi4[0], hi4[1], hi4[2], hi4[3]);
    *(ushort4*)&Bt[base + 1024] = make_ushort4(lo4[0], lo4[1], lo4[2], lo4[3]);
}

// ---------------------------------------------------------------------------
// K3: C = relu(X @ Wn) via 3-phase bf16 MFMA.
// Tile 128(M)x64(N), BK=64, 4 waves, wave tile 64x32 (acc 4x2).
// Grid 16x32 = 512 blocks = 2 blocks/CU; LDS 48 KB (fits 2-3 blocks/CU) so
// one block's MFMA overlaps the other's barrier/vmcnt drain [m114 mechanism].
// XOR-swizzled LDS chunks (pos = row*8 + (seg ^ (row&7))): staging stays
// lane-contiguous for global_load_lds, frag reads spread over all bank-quads.
__global__ __launch_bounds__(256, 2) void k_gemm4(const unsigned short* __restrict__ Ah,
        const unsigned short* __restrict__ Al, const unsigned short* __restrict__ Bt,
        float* __restrict__ out) {
    __shared__ unsigned short sAh[128 * 64], sAl[128 * 64];   // 16 KB each
    __shared__ unsigned short sBh[64 * 64],  sBl[64 * 64];    //  8 KB each
    int tid = threadIdx.x;
    int lane = tid & 63, w = tid >> 6;
    int n0 = blockIdx.x * 64, m0 = blockIdx.y * 128;
    int wm = (w >> 1) * 64, wn = (w & 1) * 32;
    int quad = lane >> 4, l16 = lane & 15;

    f32x4 acc[4][2];
    #pragma unroll
    for (int i = 0; i < 4; i++)
        #pragma unroll
        for (int j = 0; j < 2; j++) acc[i][j] = (f32x4)0.f;

    for (int it = 0; it < 16; ++it) {
        int kb = it * 64;
        __syncthreads();
        // A: 1024 chunks per buffer (128 rows x 8 segs), 4 per thread
        #pragma unroll
        for (int s = 0; s < 4; ++s) {
            int P = s * 256 + tid;
            int row = P >> 3;
            int seg = (P & 7) ^ (row & 7);
            int ldsOff = (s * 256 + w * 64) * 8;        // wave-uniform dst
            size_t ga = (size_t)(m0 + row) * 1024 + kb + seg * 8;
            gld16(&Ah[ga], &sAh[ldsOff]);
            gld16(&Al[ga], &sAl[ldsOff]);
        }
        // B: 512 chunks per buffer (64 rows x 8 segs), 2 per thread
        #pragma unroll
        for (int s = 0; s < 2; ++s) {
            int P = s * 256 + tid;
            int row = P >> 3;
            int seg = (P & 7) ^ (row & 7);
            int ldsOff = (s * 256 + w * 64) * 8;
            size_t gb = (size_t)(n0 + row) * 2048 + kb + seg * 8;
            gld16(&Bt[gb], &sBh[ldsOff]);
            gld16(&Bt[gb + 1024], &sBl[ldsOff]);
        }
        __syncthreads();
        #pragma unroll
        for (int ks = 0; ks < 2; ++ks) {
            int segk = ks * 4 + quad;
            bf16x8 ah[4], al[4], bh[2], bl[2];
            #pragma unroll
            for (int i = 0; i < 4; ++i) {
                int ra = wm + i * 16 + l16;
                int ca = (ra * 8 + (segk ^ (ra & 7))) * 8;
                ah[i] = *(const bf16x8*)&sAh[ca];
                al[i] = *(const bf16x8*)&sAl[ca];
            }
            #pragma unroll
            for (int j = 0; j < 2; ++j) {
                int rb = wn + j * 16 + l16;
                int cb = (rb * 8 + (segk ^ (rb & 7))) * 8;
                bh[j] = *(const bf16x8*)&sBh[cb];
                bl[j] = *(const bf16x8*)&sBl[cb];
            }
            #pragma unroll
            for (int i = 0; i < 4; ++i)
                #pragma unroll
                for (int j = 0; j < 2; ++j) {
                    acc[i][j] = __builtin_amdgcn_mfma_f32_16x16x32_bf16(ah[i], bh[j], acc[i][j], 0, 0, 0);
                    acc[i][j] = __builtin_amdgcn_mfma_f32_16x16x32_bf16(al[i], bh[j], acc[i][j], 0, 0, 0);
                    acc[i][j] = __builtin_amdgcn_mfma_f32_16x16x32_bf16(ah[i], bl[j], acc[i][j], 0, 0, 0);
                }
        }
    }
    // C/D layout: col = lane&15, row = quad*4 + reg  [measured m89/m91]
    #pragma unroll
    for (int i = 0; i < 4; ++i) {
        int mr = m0 + wm + i * 16 + quad * 4;
        #pragma unroll
        for (int j = 0; j < 2; ++j) {
            int nc = n0 + wn + j * 16 + l16;
            #pragma unroll
            for (int r = 0; r < 4; ++r)
                out[(size_t)(mr + r) * 1024 + nc] = fmaxf(acc[i][j][r], 0.f);
        }
    }
}

// ---------------------------------------------------------------------------
// K4: in-place row softmax, shuffle-based (2 barriers). [unchanged]
__global__ __launch_bounds__(256) void k_softmax2(float* __restrict__ C) {
    int row = blockIdx.x, t = threadIdx.x, lane = t & 63, wv = t >> 6;
    __shared__ float red[8];
    float4 v = *(float4*)&C[(size_t)row * 1024 + t * 4];
    float lm = fmaxf(fmaxf(v.x, v.y), fmaxf(v.z, v.w));
    #pragma unroll
    for (int o = 32; o; o >>= 1) lm = fmaxf(lm, __shfl_down(lm, o));
    if (lane == 0) red[wv] = lm;
    __syncthreads();
    float mx = fmaxf(fmaxf(red[0], red[1]), fmaxf(red[2], red[3]));
    float4 e;
    e.x = __expf(v.x - mx); e.y = __expf(v.y - mx);
    e.z = __expf(v.z - mx); e.w = __expf(v.w - mx);
    float ls = e.x + e.y + e.z + e.w;
    #pragma unroll
    for (int o = 32; o; o >>= 1) ls += __shfl_down(ls, o);
    if (lane == 0) red[4 + wv] = ls;
    __syncthreads();
    float inv = 1.0f / (red[4] + red[5] + red[6] + red[7]);
    e.x *= inv; e.y *= inv; e.z *= inv; e.w *= inv;
    *(float4*)&C[(size_t)row * 1024 + t * 4] = e;
}

// ---------------------------------------------------------------------------
extern "C" void kernel_launch(void* const* d_in, const int* in_sizes, int n_in,
                              void* d_out, int out_size, void* d_ws, size_t ws_size,
                              hipStream_t stream) {
    const float* X  = (const float*)d_in[0];
    const float* W  = (const float*)d_in[1];
    // d_in[2] = hidden: analytic, never read
    const float* W1 = (const float*)d_in[3];
    const float* b1 = (const float*)d_in[4];
    const float* W2 = (const float*)d_in[5];
    const float* b2 = (const float*)d_in[6];
    const float* W3 = (const float*)d_in[7];
    const float* b3 = (const float*)d_in[8];

    char* wsb = (char*)d_ws;
    float* rs            = (float*)(wsb + RS_OFF);
    float* cs_part       = (float*)(wsb + CSPART_OFF);
    unsigned short* Bt   = (unsigned short*)(wsb + BT_OFF);
    unsigned short* Ah   = (unsigned short*)(wsb + AH_OFF);
    unsigned short* Al   = (unsigned short*)(wsb + AL_OFF);
    float* out = (float*)d_out;

    k_pre<<<1088, 256, 0, stream>>>(W, X, rs, cs_part, Ah, Al);
    k_nw<<<dim3(32, 32), 256, 0, stream>>>(W, rs, cs_part, W1, b1, W2, b2, W3, b3, Bt);
    k_gemm4<<<dim3(16, 32), 256, 0, stream>>>(Ah, Al, Bt, out);
    k_softmax2<<<4096, 256, 0, stream>>>(out);
}

// Round 5
// 184.453 us; speedup vs baseline: 1.5650x; 1.0332x over previous
//
#include <hip/hip_runtime.h>
#include <hip/hip_bf16.h>
#include <stdint.h>

// out = softmax(relu(X @ new_weight)), new_weight = weight + MLP(feat)[...,0].
// hidden features collapse analytically to bit features of (n,m); layer-1 is
// rank-1 + separable -> per-row table rn[n][10] + per-col table cm[m][10],
// computed inline per k_nw block.
// GEMM (R5): fp16 2-term W-split:  logit = fp16(x) * (wh + wl),
//   wh = fp16(w), wl = fp16(w - wh)  ->  W exact to ~2^-22, only X truncated
//   at fp16 (2^-11 rel). MFMA 16x16x32_f16, 2 phases (was bf16 3-phase).
// Tile 128(M)x64(N), BK=64, LDS 32 KB, >=3 blocks/CU co-resident.
//
// 4 dispatches: k_pre (sums + X fp16 cast) -> k_nw -> k_gemm5 -> k_softmax2.
//
// ws layout (bytes):
//   rs      @ 0        : f32[1024]          row sums of weight
//   cs_part @ 4096     : f32[64][1024]      per-block partial col sums
//   Bt      @ 266240   : f16[1024][2048]    new_weight^T hi|lo   (4 MB)
//   Ah      @ 4460544  : f16[4096][1024]    fp16(X)              (8 MB)

#define RS_OFF      0
#define CSPART_OFF  4096
#define BT_OFF      266240
#define AH_OFF      4460544

typedef __attribute__((ext_vector_type(8))) _Float16 f16x8;
typedef __attribute__((ext_vector_type(4))) float f32x4;

__device__ __forceinline__ unsigned short f2h(float x) {
    _Float16 h = (_Float16)x;            // RNE
    unsigned short u;
    __builtin_memcpy(&u, &h, 2);
    return u;
}
__device__ __forceinline__ float h2f(unsigned short u) {
    _Float16 h;
    __builtin_memcpy(&h, &u, 2);
    return (float)h;
}
__device__ __forceinline__ void gld16(const void* g, void* l) {
    __builtin_amdgcn_global_load_lds(
        (const __attribute__((address_space(1))) unsigned*)g,
        (__attribute__((address_space(3))) unsigned*)l, 16, 0, 0);
}

// ---------------------------------------------------------------------------
// K1: fused. Blocks 0..63: row sums (wave per 4 rows, shuffle) + 64 partial
// colsum vectors (no atomics, no memset). Blocks 64..1087: cast X -> fp16 Ah.
__global__ __launch_bounds__(256) void k_pre(const float* __restrict__ w,
        const float* __restrict__ X, float* __restrict__ rs,
        float* __restrict__ cs_part, unsigned short* __restrict__ Ah) {
    int t = threadIdx.x;
    if (blockIdx.x < 64) {
        __shared__ float part[4][1024];
        int lane = t & 63, wv = t >> 6;
        int r0 = blockIdx.x * 16 + wv * 4;
        float ccol[16];
        #pragma unroll
        for (int j = 0; j < 16; ++j) ccol[j] = 0.f;
        #pragma unroll
        for (int rr = 0; rr < 4; ++rr) {
            int row = r0 + rr;
            float rsum = 0.f;
            #pragma unroll
            for (int j = 0; j < 16; ++j) {
                float v = w[(size_t)row * 1024 + j * 64 + lane];
                ccol[j] += v;
                rsum += v;
            }
            #pragma unroll
            for (int o = 32; o; o >>= 1) rsum += __shfl_down(rsum, o);
            if (lane == 0) rs[row] = rsum;
        }
        #pragma unroll
        for (int j = 0; j < 16; ++j) part[wv][j * 64 + lane] = ccol[j];
        __syncthreads();
        #pragma unroll
        for (int j = 0; j < 4; ++j) {
            int c = t + j * 256;
            cs_part[(size_t)blockIdx.x * 1024 + c] =
                part[0][c] + part[1][c] + part[2][c] + part[3][c];
        }
    } else {
        int b2 = blockIdx.x - 64;           // 0..1023, 4096 floats each
        #pragma unroll
        for (int p = 0; p < 4; ++p) {
            size_t idx = (size_t)b2 * 4096 + p * 1024 + t * 4;
            float4 v = *(const float4*)&X[idx];
            ushort4 h;
            h.x = f2h(v.x); h.y = f2h(v.y); h.z = f2h(v.z); h.w = f2h(v.w);
            *(ushort4*)&Ah[idx] = h;
        }
    }
}

// ---------------------------------------------------------------------------
// K2: new_weight MLP on 32x32 tiles with inline rn/cm tables and inline
// colsum reduction. Writes TRANSPOSED fp16 hi/lo: Bt[m][n]=hi, Bt[m][1024+n]=lo.
__global__ __launch_bounds__(256) void k_nw(const float* __restrict__ w,
        const float* __restrict__ rs, const float* __restrict__ cs_part,
        const float* __restrict__ W1, const float* __restrict__ b1,
        const float* __restrict__ W2, const float* __restrict__ b2,
        const float* __restrict__ W3, const float* __restrict__ b3,
        unsigned short* __restrict__ Bt) {
    __shared__ float sW1[630], sW2[100], sb1[10], sb2[10], sw3[10], sa[10];
    __shared__ float rs_loc[32], cs_loc[32];
    __shared__ float rn_loc[320], cm_loc[320];
    __shared__ float st[32][33];   // +1 pad: conflict-free column reads
    int t = threadIdx.x;
    int n0 = blockIdx.x * 32;      // weight-row base (k of gemm)
    int m0 = blockIdx.y * 32;      // weight-col base (n of gemm)
    const float inv = 1.0f / 1023.0f;

    for (int i = t; i < 630; i += 256) sW1[i] = W1[i];
    if (t < 100) sW2[t] = W2[t];
    if (t >= 128 && t < 138) { sb1[t - 128] = b1[t - 128]; sb2[t - 128] = b2[t - 128]; }
    if (t >= 160 && t < 170) sw3[t - 160] = W3[(t - 160) * 21];  // W3[:,0]
    if (t >= 192 && t < 224) rs_loc[t - 192] = rs[n0 + t - 192];
    if (t >= 224 && t < 256) {
        float s = 0.f;
        #pragma unroll
        for (int p = 0; p < 64; ++p) s += cs_part[(size_t)p * 1024 + m0 + (t - 224)];
        cs_loc[t - 224] = s;
    }
    float b30 = b3[0];
    __syncthreads();
    if (t < 10) sa[t] = sW1[t] - (sW1[10 + t] + sW1[20 + t]) * inv;
    // rn/cm tables for this block's 32 rows / 32 cols (640 values)
    for (int id = t; id < 640; id += 256) {
        int h = id % 10, i = (id / 10) & 31, side = id >= 320;
        if (!side) {
            int n = n0 + i;
            float v = rs_loc[i] * sW1[20 + h] * inv;
            #pragma unroll
            for (int j = 0; j < 10; j++) {
                float bit = (float)((n >> (9 - j)) & 1);
                v += bit * (sW1[(3 + j) * 10 + h] + sW1[(43 + j) * 10 + h]
                            - sW1[(23 + j) * 10 + h] * inv);
                v += (512.0f * inv) * sW1[(23 + j) * 10 + h];
            }
            rn_loc[i * 10 + h] = v;
        } else {
            int m = m0 + i;
            float v = cs_loc[i] * sW1[10 + h] * inv + sb1[h];
            #pragma unroll
            for (int j = 0; j < 10; j++) {
                float bit = (float)((m >> (9 - j)) & 1);
                v += bit * (sW1[(13 + j) * 10 + h] + sW1[(33 + j) * 10 + h]
                            - sW1[(53 + j) * 10 + h] * inv);
                v += (512.0f * inv) * sW1[(53 + j) * 10 + h];
            }
            cm_loc[i * 10 + h] = v;
        }
    }
    __syncthreads();
    int ml = t & 31;
    #pragma unroll
    for (int i = 0; i < 4; i++) {
        int nl = (t >> 5) + 8 * i;
        float wv = w[(size_t)(n0 + nl) * 1024 + m0 + ml];
        float h1[10];
        #pragma unroll
        for (int h = 0; h < 10; h++)
            h1[h] = fmaxf(wv * sa[h] + rn_loc[nl * 10 + h] + cm_loc[ml * 10 + h], 0.f);
        float u = b30;
        #pragma unroll
        for (int k = 0; k < 10; k++) {
            float h2 = sb2[k];
            #pragma unroll
            for (int h = 0; h < 10; h++) h2 += h1[h] * sW2[h * 10 + k];
            u += fmaxf(h2, 0.f) * sw3[k];
        }
        st[nl][ml] = wv + u;
    }
    __syncthreads();
    int mrow = t >> 3, kc = t & 7;
    unsigned short hi4[4], lo4[4];
    #pragma unroll
    for (int j = 0; j < 4; j++) {
        float v = st[kc * 4 + j][mrow];
        unsigned short h = f2h(v);
        hi4[j] = h;
        lo4[j] = f2h(v - h2f(h));
    }
    size_t base = (size_t)(m0 + mrow) * 2048 + n0 + kc * 4;
    *(ushort4*)&Bt[base]        = make_ushort4(hi4[0], hi4[1], hi4[2], hi4[3]);
    *(ushort4*)&Bt[base + 1024] = make_ushort4(lo4[0], lo4[1], lo4[2], lo4[3]);
}

// ---------------------------------------------------------------------------
// K3: C = relu(X @ Wn) via 2-phase fp16 MFMA (W split hi/lo, X single fp16).
// Tile 128(M)x64(N), BK=64, 4 waves, wave tile 64x32 (acc 4x2). LDS 32 KB ->
// 3+ blocks/CU co-resident (barrier-drain overlap, m114). Grid 16x32 = 512.
// XOR-swizzled LDS chunks (pos = row*8 + (seg ^ (row&7))): staging stays
// lane-contiguous for global_load_lds, frag reads spread over all bank-quads.
__global__ __launch_bounds__(256, 3) void k_gemm5(const unsigned short* __restrict__ Ah,
        const unsigned short* __restrict__ Bt, float* __restrict__ out) {
    __shared__ unsigned short sAh[128 * 64];                  // 16 KB
    __shared__ unsigned short sBh[64 * 64], sBl[64 * 64];     // 8 KB each
    int tid = threadIdx.x;
    int lane = tid & 63, w = tid >> 6;
    int n0 = blockIdx.x * 64, m0 = blockIdx.y * 128;
    int wm = (w >> 1) * 64, wn = (w & 1) * 32;
    int quad = lane >> 4, l16 = lane & 15;

    f32x4 acc[4][2];
    #pragma unroll
    for (int i = 0; i < 4; i++)
        #pragma unroll
        for (int j = 0; j < 2; j++) acc[i][j] = (f32x4)0.f;

    for (int it = 0; it < 16; ++it) {
        int kb = it * 64;
        __syncthreads();
        // A: 1024 chunks (128 rows x 8 segs), 4 per thread
        #pragma unroll
        for (int s = 0; s < 4; ++s) {
            int P = s * 256 + tid;
            int row = P >> 3;
            int seg = (P & 7) ^ (row & 7);
            int ldsOff = (s * 256 + w * 64) * 8;        // wave-uniform dst
            size_t ga = (size_t)(m0 + row) * 1024 + kb + seg * 8;
            gld16(&Ah[ga], &sAh[ldsOff]);
        }
        // B: 512 chunks per buffer (64 rows x 8 segs), hi+lo
        #pragma unroll
        for (int s = 0; s < 2; ++s) {
            int P = s * 256 + tid;
            int row = P >> 3;
            int seg = (P & 7) ^ (row & 7);
            int ldsOff = (s * 256 + w * 64) * 8;
            size_t gb = (size_t)(n0 + row) * 2048 + kb + seg * 8;
            gld16(&Bt[gb], &sBh[ldsOff]);
            gld16(&Bt[gb + 1024], &sBl[ldsOff]);
        }
        __syncthreads();
        #pragma unroll
        for (int ks = 0; ks < 2; ++ks) {
            int segk = ks * 4 + quad;
            f16x8 ah[4], bh[2], bl[2];
            #pragma unroll
            for (int i = 0; i < 4; ++i) {
                int ra = wm + i * 16 + l16;
                int ca = (ra * 8 + (segk ^ (ra & 7))) * 8;
                ah[i] = *(const f16x8*)&sAh[ca];
            }
            #pragma unroll
            for (int j = 0; j < 2; ++j) {
                int rb = wn + j * 16 + l16;
                int cb = (rb * 8 + (segk ^ (rb & 7))) * 8;
                bh[j] = *(const f16x8*)&sBh[cb];
                bl[j] = *(const f16x8*)&sBl[cb];
            }
            #pragma unroll
            for (int i = 0; i < 4; ++i)
                #pragma unroll
                for (int j = 0; j < 2; ++j) {
                    acc[i][j] = __builtin_amdgcn_mfma_f32_16x16x32_f16(ah[i], bh[j], acc[i][j], 0, 0, 0);
                    acc[i][j] = __builtin_amdgcn_mfma_f32_16x16x32_f16(ah[i], bl[j], acc[i][j], 0, 0, 0);
                }
        }
    }
    // C/D layout: col = lane&15, row = quad*4 + reg  [measured m89/m91]
    #pragma unroll
    for (int i = 0; i < 4; ++i) {
        int mr = m0 + wm + i * 16 + quad * 4;
        #pragma unroll
        for (int j = 0; j < 2; ++j) {
            int nc = n0 + wn + j * 16 + l16;
            #pragma unroll
            for (int r = 0; r < 4; ++r)
                out[(size_t)(mr + r) * 1024 + nc] = fmaxf(acc[i][j][r], 0.f);
        }
    }
}

// ---------------------------------------------------------------------------
// K4: in-place row softmax, shuffle-based (2 barriers). [unchanged]
__global__ __launch_bounds__(256) void k_softmax2(float* __restrict__ C) {
    int row = blockIdx.x, t = threadIdx.x, lane = t & 63, wv = t >> 6;
    __shared__ float red[8];
    float4 v = *(float4*)&C[(size_t)row * 1024 + t * 4];
    float lm = fmaxf(fmaxf(v.x, v.y), fmaxf(v.z, v.w));
    #pragma unroll
    for (int o = 32; o; o >>= 1) lm = fmaxf(lm, __shfl_down(lm, o));
    if (lane == 0) red[wv] = lm;
    __syncthreads();
    float mx = fmaxf(fmaxf(red[0], red[1]), fmaxf(red[2], red[3]));
    float4 e;
    e.x = __expf(v.x - mx); e.y = __expf(v.y - mx);
    e.z = __expf(v.z - mx); e.w = __expf(v.w - mx);
    float ls = e.x + e.y + e.z + e.w;
    #pragma unroll
    for (int o = 32; o; o >>= 1) ls += __shfl_down(ls, o);
    if (lane == 0) red[4 + wv] = ls;
    __syncthreads();
    float inv = 1.0f / (red[4] + red[5] + red[6] + red[7]);
    e.x *= inv; e.y *= inv; e.z *= inv; e.w *= inv;
    *(float4*)&C[(size_t)row * 1024 + t * 4] = e;
}

// ---------------------------------------------------------------------------
extern "C" void kernel_launch(void* const* d_in, const int* in_sizes, int n_in,
                              void* d_out, int out_size, void* d_ws, size_t ws_size,
                              hipStream_t stream) {
    const float* X  = (const float*)d_in[0];
    const float* W  = (const float*)d_in[1];
    // d_in[2] = hidden: analytic, never read
    const float* W1 = (const float*)d_in[3];
    const float* b1 = (const float*)d_in[4];
    const float* W2 = (const float*)d_in[5];
    const float* b2 = (const float*)d_in[6];
    const float* W3 = (const float*)d_in[7];
    const float* b3 = (const float*)d_in[8];

    char* wsb = (char*)d_ws;
    float* rs            = (float*)(wsb + RS_OFF);
    float* cs_part       = (float*)(wsb + CSPART_OFF);
    unsigned short* Bt   = (unsigned short*)(wsb + BT_OFF);
    unsigned short* Ah   = (unsigned short*)(wsb + AH_OFF);
    float* out = (float*)d_out;

    k_pre<<<1088, 256, 0, stream>>>(W, X, rs, cs_part, Ah);
    k_nw<<<dim3(32, 32), 256, 0, stream>>>(W, rs, cs_part, W1, b1, W2, b2, W3, b3, Bt);
    k_gemm5<<<dim3(16, 32), 256, 0, stream>>>(Ah, Bt, out);
    k_softmax2<<<4096, 256, 0, stream>>>(out);
}

// Round 6
// 179.794 us; speedup vs baseline: 1.6056x; 1.0259x over previous
//
#include <hip/hip_runtime.h>
#include <hip/hip_bf16.h>
#include <stdint.h>

// out = softmax(relu(X @ new_weight)), new_weight = weight + MLP(feat)[...,0].
// hidden features collapse analytically to bit features of (n,m); layer-1 is
// rank-1 + separable -> per-row table rn[n][10] + per-col table cm[m][10],
// computed inline per k_nw block.
// GEMM: fp16 2-term W-split:  logit = fp16(x) * (wh + wl),
//   wh = fp16(w), wl = fp16(w - wh)  ->  W exact to ~2^-22, only X truncated
//   at fp16 (2^-11 rel). MFMA 16x16x32_f16, tile 128x64, BK=64, LDS 32 KB.
// R6: (a) XCD-aware tile swizzle in gemm (per-XCD working set: A 1 MB + B
//   4 MB -> L2-resident, shared per-iter B slab across the XCD's 4 y-groups);
// (b) X-cast folded into k_nw's grid (overlaps mem-bound cast with MLP),
//   k_pre shrinks to 64 sum blocks.
//
// 4 dispatches: k_pre (sums) -> k_nw (MLP + X cast) -> k_gemm6 -> k_softmax2.
//
// ws layout (bytes):
//   rs      @ 0        : f32[1024]          row sums of weight
//   cs_part @ 4096     : f32[64][1024]      per-block partial col sums
//   Bt      @ 266240   : f16[1024][2048]    new_weight^T hi|lo   (4 MB)
//   Ah      @ 4460544  : f16[4096][1024]    fp16(X)              (8 MB)

#define RS_OFF      0
#define CSPART_OFF  4096
#define BT_OFF      266240
#define AH_OFF      4460544

typedef __attribute__((ext_vector_type(8))) _Float16 f16x8;
typedef __attribute__((ext_vector_type(4))) float f32x4;

__device__ __forceinline__ unsigned short f2h(float x) {
    _Float16 h = (_Float16)x;            // RNE
    unsigned short u;
    __builtin_memcpy(&u, &h, 2);
    return u;
}
__device__ __forceinline__ float h2f(unsigned short u) {
    _Float16 h;
    __builtin_memcpy(&h, &u, 2);
    return (float)h;
}
__device__ __forceinline__ void gld16(const void* g, void* l) {
    __builtin_amdgcn_global_load_lds(
        (const __attribute__((address_space(1))) unsigned*)g,
        (__attribute__((address_space(3))) unsigned*)l, 16, 0, 0);
}

// ---------------------------------------------------------------------------
// K1: row sums (wave per 4 rows, shuffle) + 64 partial colsum vectors.
__global__ __launch_bounds__(256) void k_pre(const float* __restrict__ w,
        float* __restrict__ rs, float* __restrict__ cs_part) {
    __shared__ float part[4][1024];
    int t = threadIdx.x;
    int lane = t & 63, wv = t >> 6;
    int r0 = blockIdx.x * 16 + wv * 4;
    float ccol[16];
    #pragma unroll
    for (int j = 0; j < 16; ++j) ccol[j] = 0.f;
    #pragma unroll
    for (int rr = 0; rr < 4; ++rr) {
        int row = r0 + rr;
        float rsum = 0.f;
        #pragma unroll
        for (int j = 0; j < 16; ++j) {
            float v = w[(size_t)row * 1024 + j * 64 + lane];
            ccol[j] += v;
            rsum += v;
        }
        #pragma unroll
        for (int o = 32; o; o >>= 1) rsum += __shfl_down(rsum, o);
        if (lane == 0) rs[row] = rsum;
    }
    #pragma unroll
    for (int j = 0; j < 16; ++j) part[wv][j * 64 + lane] = ccol[j];
    __syncthreads();
    #pragma unroll
    for (int j = 0; j < 4; ++j) {
        int c = t + j * 256;
        cs_part[(size_t)blockIdx.x * 1024 + c] =
            part[0][c] + part[1][c] + part[2][c] + part[3][c];
    }
}

// ---------------------------------------------------------------------------
// K2: blocks 0..1023: new_weight MLP on 32x32 tiles (inline rn/cm tables +
// colsum reduction), writing TRANSPOSED fp16 hi/lo Bt. Blocks 1024..2047:
// cast X -> fp16 Ah (memory-bound; overlaps the compute-bound MLP blocks).
__global__ __launch_bounds__(256) void k_nw(const float* __restrict__ w,
        const float* __restrict__ X,
        const float* __restrict__ rs, const float* __restrict__ cs_part,
        const float* __restrict__ W1, const float* __restrict__ b1,
        const float* __restrict__ W2, const float* __restrict__ b2,
        const float* __restrict__ W3, const float* __restrict__ b3,
        unsigned short* __restrict__ Bt, unsigned short* __restrict__ Ah) {
    __shared__ float sW1[630], sW2[100], sb1[10], sb2[10], sw3[10], sa[10];
    __shared__ float rs_loc[32], cs_loc[32];
    __shared__ float rn_loc[320], cm_loc[320];
    __shared__ float st[32][33];   // +1 pad: conflict-free column reads
    int t = threadIdx.x;
    if (blockIdx.x >= 1024) {
        int b2x = blockIdx.x - 1024;        // 0..1023, 4096 floats each
        #pragma unroll
        for (int p = 0; p < 4; ++p) {
            size_t idx = (size_t)b2x * 4096 + p * 1024 + t * 4;
            float4 v = *(const float4*)&X[idx];
            ushort4 h;
            h.x = f2h(v.x); h.y = f2h(v.y); h.z = f2h(v.z); h.w = f2h(v.w);
            *(ushort4*)&Ah[idx] = h;
        }
        return;
    }
    int n0 = (blockIdx.x & 31) * 32;   // weight-row base (k of gemm)
    int m0 = (blockIdx.x >> 5) * 32;   // weight-col base (n of gemm)
    const float inv = 1.0f / 1023.0f;

    for (int i = t; i < 630; i += 256) sW1[i] = W1[i];
    if (t < 100) sW2[t] = W2[t];
    if (t >= 128 && t < 138) { sb1[t - 128] = b1[t - 128]; sb2[t - 128] = b2[t - 128]; }
    if (t >= 160 && t < 170) sw3[t - 160] = W3[(t - 160) * 21];  // W3[:,0]
    if (t >= 192 && t < 224) rs_loc[t - 192] = rs[n0 + t - 192];
    if (t >= 224 && t < 256) {
        float s = 0.f;
        #pragma unroll
        for (int p = 0; p < 64; ++p) s += cs_part[(size_t)p * 1024 + m0 + (t - 224)];
        cs_loc[t - 224] = s;
    }
    float b30 = b3[0];
    __syncthreads();
    if (t < 10) sa[t] = sW1[t] - (sW1[10 + t] + sW1[20 + t]) * inv;
    // rn/cm tables for this block's 32 rows / 32 cols (640 values)
    for (int id = t; id < 640; id += 256) {
        int h = id % 10, i = (id / 10) & 31, side = id >= 320;
        if (!side) {
            int n = n0 + i;
            float v = rs_loc[i] * sW1[20 + h] * inv;
            #pragma unroll
            for (int j = 0; j < 10; j++) {
                float bit = (float)((n >> (9 - j)) & 1);
                v += bit * (sW1[(3 + j) * 10 + h] + sW1[(43 + j) * 10 + h]
                            - sW1[(23 + j) * 10 + h] * inv);
                v += (512.0f * inv) * sW1[(23 + j) * 10 + h];
            }
            rn_loc[i * 10 + h] = v;
        } else {
            int m = m0 + i;
            float v = cs_loc[i] * sW1[10 + h] * inv + sb1[h];
            #pragma unroll
            for (int j = 0; j < 10; j++) {
                float bit = (float)((m >> (9 - j)) & 1);
                v += bit * (sW1[(13 + j) * 10 + h] + sW1[(33 + j) * 10 + h]
                            - sW1[(53 + j) * 10 + h] * inv);
                v += (512.0f * inv) * sW1[(53 + j) * 10 + h];
            }
            cm_loc[i * 10 + h] = v;
        }
    }
    __syncthreads();
    int ml = t & 31;
    #pragma unroll
    for (int i = 0; i < 4; i++) {
        int nl = (t >> 5) + 8 * i;
        float wv = w[(size_t)(n0 + nl) * 1024 + m0 + ml];
        float h1[10];
        #pragma unroll
        for (int h = 0; h < 10; h++)
            h1[h] = fmaxf(wv * sa[h] + rn_loc[nl * 10 + h] + cm_loc[ml * 10 + h], 0.f);
        float u = b30;
        #pragma unroll
        for (int k = 0; k < 10; k++) {
            float h2 = sb2[k];
            #pragma unroll
            for (int h = 0; h < 10; h++) h2 += h1[h] * sW2[h * 10 + k];
            u += fmaxf(h2, 0.f) * sw3[k];
        }
        st[nl][ml] = wv + u;
    }
    __syncthreads();
    int mrow = t >> 3, kc = t & 7;
    unsigned short hi4[4], lo4[4];
    #pragma unroll
    for (int j = 0; j < 4; j++) {
        float v = st[kc * 4 + j][mrow];
        unsigned short h = f2h(v);
        hi4[j] = h;
        lo4[j] = f2h(v - h2f(h));
    }
    size_t base = (size_t)(m0 + mrow) * 2048 + n0 + kc * 4;
    *(ushort4*)&Bt[base]        = make_ushort4(hi4[0], hi4[1], hi4[2], hi4[3]);
    *(ushort4*)&Bt[base + 1024] = make_ushort4(lo4[0], lo4[1], lo4[2], lo4[3]);
}

// ---------------------------------------------------------------------------
// K3: C = relu(X @ Wn) via 2-phase fp16 MFMA (W split hi/lo, X single fp16).
// Tile 128(M)x64(N), BK=64, 4 waves, wave tile 64x32 (acc 4x2), LDS 32 KB.
// XCD-aware swizzle (dispatch round-robins blocks over 8 XCDs): XCD k owns
// m-groups {4k..4k+3} x all 16 n-blocks -> per-XCD working set A 1 MB +
// B 4 MB stays L2-resident; per-iter B slab shared by the XCD's 4 y-groups.
// XOR-swizzled LDS chunks (pos = row*8 + (seg ^ (row&7))): staging stays
// lane-contiguous for global_load_lds, frag reads spread over all bank-quads.
__global__ __launch_bounds__(256, 3) void k_gemm6(const unsigned short* __restrict__ Ah,
        const unsigned short* __restrict__ Bt, float* __restrict__ out) {
    __shared__ unsigned short sAh[128 * 64];                  // 16 KB
    __shared__ unsigned short sBh[64 * 64], sBl[64 * 64];     // 8 KB each
    int tid = threadIdx.x;
    int lane = tid & 63, w = tid >> 6;
    // tile swizzle: b = (xcd, slot); ty = xcd*4 + slot/16, tx = slot%16
    int b = blockIdx.x;
    int xcd = b & 7, s = b >> 3;
    int ty = (xcd << 2) | (s >> 4);
    int tx = s & 15;
    int n0 = tx * 64, m0 = ty * 128;
    int wm = (w >> 1) * 64, wn = (w & 1) * 32;
    int quad = lane >> 4, l16 = lane & 15;

    f32x4 acc[4][2];
    #pragma unroll
    for (int i = 0; i < 4; i++)
        #pragma unroll
        for (int j = 0; j < 2; j++) acc[i][j] = (f32x4)0.f;

    for (int it = 0; it < 16; ++it) {
        int kb = it * 64;
        __syncthreads();
        // A: 1024 chunks (128 rows x 8 segs), 4 per thread
        #pragma unroll
        for (int s2 = 0; s2 < 4; ++s2) {
            int P = s2 * 256 + tid;
            int row = P >> 3;
            int seg = (P & 7) ^ (row & 7);
            int ldsOff = (s2 * 256 + w * 64) * 8;       // wave-uniform dst
            size_t ga = (size_t)(m0 + row) * 1024 + kb + seg * 8;
            gld16(&Ah[ga], &sAh[ldsOff]);
        }
        // B: 512 chunks per buffer (64 rows x 8 segs), hi+lo
        #pragma unroll
        for (int s2 = 0; s2 < 2; ++s2) {
            int P = s2 * 256 + tid;
            int row = P >> 3;
            int seg = (P & 7) ^ (row & 7);
            int ldsOff = (s2 * 256 + w * 64) * 8;
            size_t gb = (size_t)(n0 + row) * 2048 + kb + seg * 8;
            gld16(&Bt[gb], &sBh[ldsOff]);
            gld16(&Bt[gb + 1024], &sBl[ldsOff]);
        }
        __syncthreads();
        #pragma unroll
        for (int ks = 0; ks < 2; ++ks) {
            int segk = ks * 4 + quad;
            f16x8 ah[4], bh[2], bl[2];
            #pragma unroll
            for (int i = 0; i < 4; ++i) {
                int ra = wm + i * 16 + l16;
                int ca = (ra * 8 + (segk ^ (ra & 7))) * 8;
                ah[i] = *(const f16x8*)&sAh[ca];
            }
            #pragma unroll
            for (int j = 0; j < 2; ++j) {
                int rb = wn + j * 16 + l16;
                int cb = (rb * 8 + (segk ^ (rb & 7))) * 8;
                bh[j] = *(const f16x8*)&sBh[cb];
                bl[j] = *(const f16x8*)&sBl[cb];
            }
            #pragma unroll
            for (int i = 0; i < 4; ++i)
                #pragma unroll
                for (int j = 0; j < 2; ++j) {
                    acc[i][j] = __builtin_amdgcn_mfma_f32_16x16x32_f16(ah[i], bh[j], acc[i][j], 0, 0, 0);
                    acc[i][j] = __builtin_amdgcn_mfma_f32_16x16x32_f16(ah[i], bl[j], acc[i][j], 0, 0, 0);
                }
        }
    }
    // C/D layout: col = lane&15, row = quad*4 + reg  [measured m89/m91]
    #pragma unroll
    for (int i = 0; i < 4; ++i) {
        int mr = m0 + wm + i * 16 + quad * 4;
        #pragma unroll
        for (int j = 0; j < 2; ++j) {
            int nc = n0 + wn + j * 16 + l16;
            #pragma unroll
            for (int r = 0; r < 4; ++r)
                out[(size_t)(mr + r) * 1024 + nc] = fmaxf(acc[i][j][r], 0.f);
        }
    }
}

// ---------------------------------------------------------------------------
// K4: in-place row softmax, shuffle-based (2 barriers). [unchanged]
__global__ __launch_bounds__(256) void k_softmax2(float* __restrict__ C) {
    int row = blockIdx.x, t = threadIdx.x, lane = t & 63, wv = t >> 6;
    __shared__ float red[8];
    float4 v = *(float4*)&C[(size_t)row * 1024 + t * 4];
    float lm = fmaxf(fmaxf(v.x, v.y), fmaxf(v.z, v.w));
    #pragma unroll
    for (int o = 32; o; o >>= 1) lm = fmaxf(lm, __shfl_down(lm, o));
    if (lane == 0) red[wv] = lm;
    __syncthreads();
    float mx = fmaxf(fmaxf(red[0], red[1]), fmaxf(red[2], red[3]));
    float4 e;
    e.x = __expf(v.x - mx); e.y = __expf(v.y - mx);
    e.z = __expf(v.z - mx); e.w = __expf(v.w - mx);
    float ls = e.x + e.y + e.z + e.w;
    #pragma unroll
    for (int o = 32; o; o >>= 1) ls += __shfl_down(ls, o);
    if (lane == 0) red[4 + wv] = ls;
    __syncthreads();
    float inv = 1.0f / (red[4] + red[5] + red[6] + red[7]);
    e.x *= inv; e.y *= inv; e.z *= inv; e.w *= inv;
    *(float4*)&C[(size_t)row * 1024 + t * 4] = e;
}

// ---------------------------------------------------------------------------
extern "C" void kernel_launch(void* const* d_in, const int* in_sizes, int n_in,
                              void* d_out, int out_size, void* d_ws, size_t ws_size,
                              hipStream_t stream) {
    const float* X  = (const float*)d_in[0];
    const float* W  = (const float*)d_in[1];
    // d_in[2] = hidden: analytic, never read
    const float* W1 = (const float*)d_in[3];
    const float* b1 = (const float*)d_in[4];
    const float* W2 = (const float*)d_in[5];
    const float* b2 = (const float*)d_in[6];
    const float* W3 = (const float*)d_in[7];
    const float* b3 = (const float*)d_in[8];

    char* wsb = (char*)d_ws;
    float* rs            = (float*)(wsb + RS_OFF);
    float* cs_part       = (float*)(wsb + CSPART_OFF);
    unsigned short* Bt   = (unsigned short*)(wsb + BT_OFF);
    unsigned short* Ah   = (unsigned short*)(wsb + AH_OFF);
    float* out = (float*)d_out;

    k_pre<<<64, 256, 0, stream>>>(W, rs, cs_part);
    k_nw<<<2048, 256, 0, stream>>>(W, X, rs, cs_part, W1, b1, W2, b2, W3, b3, Bt, Ah);
    k_gemm6<<<512, 256, 0, stream>>>(Ah, Bt, out);
    k_softmax2<<<4096, 256, 0, stream>>>(out);
}